// Round 1
// baseline (558.402 us; speedup 1.0000x reference)
//
#include <hip/hip_runtime.h>

#define D 128
#define TM 32

// ---------------- precompute kernels ----------------

__global__ void init_kernel(int* __restrict__ deg, int* __restrict__ cursor, int n) {
    int i = blockIdx.x * blockDim.x + threadIdx.x;
    if (i < n) { deg[i] = 1; cursor[i] = 0; }   // 1 = self-loop
}

__global__ void count_kernel(const int* __restrict__ dst, int* __restrict__ deg, int e) {
    int i = blockIdx.x * blockDim.x + threadIdx.x;
    if (i < e) atomicAdd(&deg[dst[i]], 1);
}

__global__ void dinv_kernel(const int* __restrict__ deg, float* __restrict__ dinv, int n) {
    int i = blockIdx.x * blockDim.x + threadIdx.x;
    if (i < n) dinv[i] = rsqrtf((float)deg[i]);
}

// single-block exclusive scan of (deg[i]-1) over n elements -> offsets
__global__ void scan_kernel(const int* __restrict__ deg, int* __restrict__ offsets, int n) {
    __shared__ int sums[1024];
    int t = threadIdx.x;
    int chunk = (n + 1023) >> 10;
    int s0 = t * chunk;
    int s1 = s0 + chunk; if (s1 > n) s1 = n;
    int s = 0;
    for (int i = s0; i < s1; ++i) s += deg[i] - 1;
    sums[t] = s;
    __syncthreads();
    for (int off = 1; off < 1024; off <<= 1) {
        int v = (t >= off) ? sums[t - off] : 0;
        __syncthreads();
        sums[t] += v;
        __syncthreads();
    }
    int excl = (t == 0) ? 0 : sums[t - 1];
    for (int i = s0; i < s1; ++i) {
        offsets[i] = excl;
        excl += deg[i] - 1;
    }
}

__global__ void fill_kernel(const int* __restrict__ src, const int* __restrict__ dst,
                            const int* __restrict__ offsets, int* __restrict__ cursor,
                            const float* __restrict__ dinv,
                            int* __restrict__ csr_src, float* __restrict__ csr_wt, int e) {
    int i = blockIdx.x * blockDim.x + threadIdx.x;
    if (i < e) {
        int d = dst[i], s = src[i];
        int pos = offsets[d] + atomicAdd(&cursor[d], 1);
        csr_src[pos] = s;
        csr_wt[pos]  = dinv[s];
    }
}

// ---------------- dense transform: out[N][128] = A[N][128] @ W[128][128] ----------------
// 32 rows per block, 256 threads, thread computes 4 rows x 4 cols.
// W staged transposed in LDS in two 64-k halves (keeps LDS < 64KB, 3 blocks/CU).
__global__ __launch_bounds__(256, 3) void gemm_kernel(const float* __restrict__ A,
                                                      const float* __restrict__ Wg,
                                                      float* __restrict__ outp, int n) {
    __shared__ float As[TM][132];    // +4 pad keeps 16B align, spreads banks
    __shared__ float Wt[128][68];    // Wt[c][kk] for current 64-k half

    int t = threadIdx.x;
    int rowBase = blockIdx.x * TM;

    // stage A tile (float4, coalesced)
    for (int idx = t; idx < TM * 32; idx += 256) {
        int r  = idx >> 5;
        int c4 = (idx & 31) << 2;
        int gr = rowBase + r;
        float4 v = (gr < n) ? *reinterpret_cast<const float4*>(A + (size_t)gr * D + c4)
                            : make_float4(0.f, 0.f, 0.f, 0.f);
        *reinterpret_cast<float4*>(&As[r][c4]) = v;
    }

    int c0 = t & 31;
    int rb = (t >> 5) << 2;          // 0,4,...,28
    float acc[4][4] = {};

    for (int kp = 0; kp < 128; kp += 64) {
        __syncthreads();             // protect Wt (and cover As on first pass)
        // stage transposed W half: Wt[c][kk] = W[kp+kk][c]  (coalesced global read)
        for (int idx = t; idx < 64 * 128; idx += 256) {
            int kk = idx >> 7;
            int c  = idx & 127;
            Wt[c][kk] = Wg[(kp + kk) * D + c];
        }
        __syncthreads();

        for (int kk = 0; kk < 64; kk += 4) {
            float4 w0 = *reinterpret_cast<const float4*>(&Wt[c0][kk]);
            float4 w1 = *reinterpret_cast<const float4*>(&Wt[c0 + 32][kk]);
            float4 w2 = *reinterpret_cast<const float4*>(&Wt[c0 + 64][kk]);
            float4 w3 = *reinterpret_cast<const float4*>(&Wt[c0 + 96][kk]);
            #pragma unroll
            for (int r = 0; r < 4; ++r) {
                float4 a = *reinterpret_cast<const float4*>(&As[rb + r][kp + kk]);
                acc[r][0] += a.x * w0.x + a.y * w0.y + a.z * w0.z + a.w * w0.w;
                acc[r][1] += a.x * w1.x + a.y * w1.y + a.z * w1.z + a.w * w1.w;
                acc[r][2] += a.x * w2.x + a.y * w2.y + a.z * w2.z + a.w * w2.w;
                acc[r][3] += a.x * w3.x + a.y * w3.y + a.z * w3.z + a.w * w3.w;
            }
        }
    }

    #pragma unroll
    for (int r = 0; r < 4; ++r) {
        int gr = rowBase + rb + r;
        if (gr < n) {
            float* o = outp + (size_t)gr * D;
            o[c0]      = acc[r][0];
            o[c0 + 32] = acc[r][1];
            o[c0 + 64] = acc[r][2];
            o[c0 + 96] = acc[r][3];
        }
    }
}

// ---------------- aggregation: out[d] = relu?( dinv[d]*(sum_e wt_e*xw[src_e]) + dinv[d]^2*xw[d] + b ) ----
// one wave64 per node; half-wave per edge (float4/lane covers the 128-dim row)
__global__ __launch_bounds__(256) void agg_kernel(const float* __restrict__ xw,
                                                  const int* __restrict__ csr_src,
                                                  const float* __restrict__ csr_wt,
                                                  const int* __restrict__ offsets,
                                                  const int* __restrict__ deg,
                                                  const float* __restrict__ dinv,
                                                  const float* __restrict__ bias,
                                                  float* __restrict__ outp,
                                                  int n, int do_relu) {
    int wave = (blockIdx.x * blockDim.x + threadIdx.x) >> 6;
    int lane = threadIdx.x & 63;
    if (wave >= n) return;
    int node = wave;
    int half = lane >> 5;
    int l32  = lane & 31;

    int base = offsets[node];
    int cnt  = deg[node] - 1;

    float4 acc = make_float4(0.f, 0.f, 0.f, 0.f);
    int j = 0;
    for (; j + 2 <= cnt; j += 2) {
        int e = base + j + half;
        int s = csr_src[e];
        float w = csr_wt[e];
        float4 v = *reinterpret_cast<const float4*>(xw + (size_t)s * D + (l32 << 2));
        acc.x += w * v.x; acc.y += w * v.y; acc.z += w * v.z; acc.w += w * v.w;
    }
    if (j < cnt && half == 0) {
        int e = base + j;
        int s = csr_src[e];
        float w = csr_wt[e];
        float4 v = *reinterpret_cast<const float4*>(xw + (size_t)s * D + (l32 << 2));
        acc.x += w * v.x; acc.y += w * v.y; acc.z += w * v.z; acc.w += w * v.w;
    }

    // fold upper half-wave into lower (same columns)
    acc.x += __shfl_down(acc.x, 32);
    acc.y += __shfl_down(acc.y, 32);
    acc.z += __shfl_down(acc.z, 32);
    acc.w += __shfl_down(acc.w, 32);

    if (half == 0) {
        float di = dinv[node];
        float4 vs = *reinterpret_cast<const float4*>(xw + (size_t)node * D + (l32 << 2));
        float4 b  = *reinterpret_cast<const float4*>(bias + (l32 << 2));
        float4 r;
        r.x = di * (acc.x + di * vs.x) + b.x;
        r.y = di * (acc.y + di * vs.y) + b.y;
        r.z = di * (acc.z + di * vs.z) + b.z;
        r.w = di * (acc.w + di * vs.w) + b.w;
        if (do_relu) {
            r.x = fmaxf(r.x, 0.f); r.y = fmaxf(r.y, 0.f);
            r.z = fmaxf(r.z, 0.f); r.w = fmaxf(r.w, 0.f);
        }
        *reinterpret_cast<float4*>(outp + (size_t)node * D + (l32 << 2)) = r;
    }
}

// ---------------- head: out[n] = h[n,:] . Wfc + bfc ----------------
__global__ __launch_bounds__(256) void fc_kernel(const float* __restrict__ h,
                                                 const float* __restrict__ Wfc,
                                                 const float* __restrict__ bfc,
                                                 float* __restrict__ outp, int n) {
    int wave = (blockIdx.x * blockDim.x + threadIdx.x) >> 6;
    int lane = threadIdx.x & 63;
    if (wave >= n) return;
    float2 v = *reinterpret_cast<const float2*>(h + (size_t)wave * D + (lane << 1));
    float2 w = *reinterpret_cast<const float2*>(Wfc + (lane << 1));
    float s = v.x * w.x + v.y * w.y;
    #pragma unroll
    for (int off = 32; off > 0; off >>= 1) s += __shfl_down(s, off);
    if (lane == 0) outp[wave] = s + bfc[0];
}

// ---------------- launch ----------------

extern "C" void kernel_launch(void* const* d_in, const int* in_sizes, int n_in,
                              void* d_out, int out_size, void* d_ws, size_t ws_size,
                              hipStream_t stream) {
    const float* x   = (const float*)d_in[0];
    const int*   ei  = (const int*)d_in[1];
    const float* W1  = (const float*)d_in[2];
    const float* b1  = (const float*)d_in[3];
    const float* W2  = (const float*)d_in[4];
    const float* b2  = (const float*)d_in[5];
    const float* W3  = (const float*)d_in[6];
    const float* b3  = (const float*)d_in[7];
    const float* Wfc = (const float*)d_in[8];
    const float* bfc = (const float*)d_in[9];
    float* outp = (float*)d_out;

    const int n = in_sizes[0] / D;        // 50000
    const int e = in_sizes[1] / 2;        // 800000
    const int* src = ei;
    const int* dst = ei + e;

    char* ws = (char*)d_ws;
    size_t off = 0;
    auto alloc = [&](size_t bytes) {
        void* p = ws + off;
        off += (bytes + 255) & ~(size_t)255;
        return p;
    };
    int*   deg     = (int*)alloc((size_t)n * 4);
    int*   cursor  = (int*)alloc((size_t)n * 4);
    int*   offsets = (int*)alloc((size_t)n * 4);
    float* dinv    = (float*)alloc((size_t)n * 4);
    int*   csr_src = (int*)alloc((size_t)e * 4);
    float* csr_wt  = (float*)alloc((size_t)e * 4);
    float* buf0    = (float*)alloc((size_t)n * D * 4);
    float* buf1    = (float*)alloc((size_t)n * D * 4);

    int nb256 = (n + 255) / 256;
    int eb256 = (e + 255) / 256;

    init_kernel <<<nb256, 256, 0, stream>>>(deg, cursor, n);
    count_kernel<<<eb256, 256, 0, stream>>>(dst, deg, e);
    dinv_kernel <<<nb256, 256, 0, stream>>>(deg, dinv, n);
    scan_kernel <<<1, 1024, 0, stream>>>(deg, offsets, n);
    fill_kernel <<<eb256, 256, 0, stream>>>(src, dst, offsets, cursor, dinv, csr_src, csr_wt, e);

    int gemm_blocks = (n + TM - 1) / TM;
    int agg_blocks  = (n + 3) / 4;        // 4 waves/block, wave per node
    int fc_blocks   = ((size_t)n * 64 + 255) / 256;

    // layer 1: x -> buf0 -> buf1
    gemm_kernel<<<gemm_blocks, 256, 0, stream>>>(x, W1, buf0, n);
    agg_kernel <<<agg_blocks, 256, 0, stream>>>(buf0, csr_src, csr_wt, offsets, deg, dinv, b1, buf1, n, 1);
    // layer 2: buf1 -> buf0 -> buf1
    gemm_kernel<<<gemm_blocks, 256, 0, stream>>>(buf1, W2, buf0, n);
    agg_kernel <<<agg_blocks, 256, 0, stream>>>(buf0, csr_src, csr_wt, offsets, deg, dinv, b2, buf1, n, 1);
    // layer 3: buf1 -> buf0 -> buf1
    gemm_kernel<<<gemm_blocks, 256, 0, stream>>>(buf1, W3, buf0, n);
    agg_kernel <<<agg_blocks, 256, 0, stream>>>(buf0, csr_src, csr_wt, offsets, deg, dinv, b3, buf1, n, 1);
    // head
    fc_kernel  <<<fc_blocks, 256, 0, stream>>>(buf1, Wfc, bfc, outp, n);
}

// Round 2
// 502.583 us; speedup vs baseline: 1.1111x; 1.1111x over previous
//
#include <hip/hip_runtime.h>

#define D 128
#define TM 32
#define SCAN_ELEMS 4096   // elements per scan block (256 threads x 16)

// ---------------- precompute kernels ----------------
// deg[] counts REAL edges only (self-loop handled as +1 at use sites).

__global__ void count_kernel(const int* __restrict__ dst, int* __restrict__ deg, int e) {
    int i = blockIdx.x * blockDim.x + threadIdx.x;
    if (i < e) atomicAdd(&deg[dst[i]], 1);
}

// ---- hierarchical scan: A) block sums  B) scan block sums  C) final offsets + dinv ----

__global__ __launch_bounds__(256) void scanA_kernel(const int* __restrict__ deg,
                                                    int* __restrict__ blkSums, int n) {
    __shared__ int waveSums[4];
    int t = threadIdx.x;
    int base = blockIdx.x * SCAN_ELEMS + t * 16;
    int s = 0;
    if (base + 16 <= n) {
        const int4* p = reinterpret_cast<const int4*>(deg + base);
        #pragma unroll
        for (int k = 0; k < 4; ++k) {
            int4 v = p[k];
            s += v.x + v.y + v.z + v.w;
        }
    } else {
        for (int k = 0; k < 16; ++k) {
            int i = base + k;
            if (i < n) s += deg[i];
        }
    }
    // wave reduce
    #pragma unroll
    for (int off = 32; off > 0; off >>= 1) s += __shfl_down(s, off);
    int lane = t & 63, w = t >> 6;
    if (lane == 0) waveSums[w] = s;
    __syncthreads();
    if (t == 0) blkSums[blockIdx.x] = waveSums[0] + waveSums[1] + waveSums[2] + waveSums[3];
}

// single wave scans up to 64 block sums -> exclusive block offsets
__global__ void scanB_kernel(const int* __restrict__ blkSums, int* __restrict__ blkOff, int nblk) {
    int t = threadIdx.x;   // 64 threads
    int s = (t < nblk) ? blkSums[t] : 0;
    int orig = s;
    #pragma unroll
    for (int off = 1; off < 64; off <<= 1) {
        int u = __shfl_up(s, off);
        if (t >= off) s += u;
    }
    if (t < nblk) blkOff[t] = s - orig;   // exclusive
}

__global__ __launch_bounds__(256) void scanC_kernel(const int* __restrict__ deg,
                                                    const int* __restrict__ blkOff,
                                                    int* __restrict__ offsets,
                                                    float* __restrict__ dinv, int n) {
    __shared__ int waveSums[4];
    int t = threadIdx.x;
    int lane = t & 63, w = t >> 6;
    int base = blockIdx.x * SCAN_ELEMS + t * 16;

    int v[16];
    int s = 0;
    #pragma unroll
    for (int k = 0; k < 16; ++k) {
        int i = base + k;
        int d = (i < n) ? deg[i] : 0;
        v[k] = d;
        s += d;
    }
    // wave inclusive scan of thread sums
    int incl = s;
    #pragma unroll
    for (int off = 1; off < 64; off <<= 1) {
        int u = __shfl_up(incl, off);
        if (lane >= off) incl += u;
    }
    if (lane == 63) waveSums[w] = incl;
    __syncthreads();
    int waveOff = 0;
    for (int i = 0; i < 4; ++i) if (i < w) waveOff += waveSums[i];
    int off0 = blkOff[blockIdx.x] + waveOff + incl - s;  // exclusive prefix for this thread

    #pragma unroll
    for (int k = 0; k < 16; ++k) {
        int i = base + k;
        if (i < n) {
            offsets[i] = off0;
            dinv[i] = rsqrtf((float)(v[k] + 1));   // +1 self-loop
            off0 += v[k];
        }
    }
}

__global__ void fill_kernel(const int* __restrict__ src, const int* __restrict__ dst,
                            const int* __restrict__ offsets, int* __restrict__ cursor,
                            const float* __restrict__ dinv,
                            int* __restrict__ csr_src, float* __restrict__ csr_wt, int e) {
    int i = blockIdx.x * blockDim.x + threadIdx.x;
    if (i < e) {
        int d = dst[i], s = src[i];
        int pos = offsets[d] + atomicAdd(&cursor[d], 1);
        csr_src[pos] = s;
        csr_wt[pos]  = dinv[s];
    }
}

// ---------------- dense transform: out[N][128] = A[N][128] @ W[128][128] ----------------
__global__ __launch_bounds__(256, 3) void gemm_kernel(const float* __restrict__ A,
                                                      const float* __restrict__ Wg,
                                                      float* __restrict__ outp, int n) {
    __shared__ float As[TM][132];
    __shared__ float Wt[128][68];

    int t = threadIdx.x;
    int rowBase = blockIdx.x * TM;

    for (int idx = t; idx < TM * 32; idx += 256) {
        int r  = idx >> 5;
        int c4 = (idx & 31) << 2;
        int gr = rowBase + r;
        float4 v = (gr < n) ? *reinterpret_cast<const float4*>(A + (size_t)gr * D + c4)
                            : make_float4(0.f, 0.f, 0.f, 0.f);
        *reinterpret_cast<float4*>(&As[r][c4]) = v;
    }

    int c0 = t & 31;
    int rb = (t >> 5) << 2;
    float acc[4][4] = {};

    for (int kp = 0; kp < 128; kp += 64) {
        __syncthreads();
        for (int idx = t; idx < 64 * 128; idx += 256) {
            int kk = idx >> 7;
            int c  = idx & 127;
            Wt[c][kk] = Wg[(kp + kk) * D + c];
        }
        __syncthreads();

        for (int kk = 0; kk < 64; kk += 4) {
            float4 w0 = *reinterpret_cast<const float4*>(&Wt[c0][kk]);
            float4 w1 = *reinterpret_cast<const float4*>(&Wt[c0 + 32][kk]);
            float4 w2 = *reinterpret_cast<const float4*>(&Wt[c0 + 64][kk]);
            float4 w3 = *reinterpret_cast<const float4*>(&Wt[c0 + 96][kk]);
            #pragma unroll
            for (int r = 0; r < 4; ++r) {
                float4 a = *reinterpret_cast<const float4*>(&As[rb + r][kp + kk]);
                acc[r][0] += a.x * w0.x + a.y * w0.y + a.z * w0.z + a.w * w0.w;
                acc[r][1] += a.x * w1.x + a.y * w1.y + a.z * w1.z + a.w * w1.w;
                acc[r][2] += a.x * w2.x + a.y * w2.y + a.z * w2.z + a.w * w2.w;
                acc[r][3] += a.x * w3.x + a.y * w3.y + a.z * w3.z + a.w * w3.w;
            }
        }
    }

    #pragma unroll
    for (int r = 0; r < 4; ++r) {
        int gr = rowBase + rb + r;
        if (gr < n) {
            float* o = outp + (size_t)gr * D;
            o[c0]      = acc[r][0];
            o[c0 + 32] = acc[r][1];
            o[c0 + 64] = acc[r][2];
            o[c0 + 96] = acc[r][3];
        }
    }
}

// ---------------- aggregation ----------------
__global__ __launch_bounds__(256) void agg_kernel(const float* __restrict__ xw,
                                                  const int* __restrict__ csr_src,
                                                  const float* __restrict__ csr_wt,
                                                  const int* __restrict__ offsets,
                                                  const int* __restrict__ deg,
                                                  const float* __restrict__ dinv,
                                                  const float* __restrict__ bias,
                                                  float* __restrict__ outp,
                                                  int n, int do_relu) {
    int wave = (blockIdx.x * blockDim.x + threadIdx.x) >> 6;
    int lane = threadIdx.x & 63;
    if (wave >= n) return;
    int node = wave;
    int half = lane >> 5;
    int l32  = lane & 31;

    int base = offsets[node];
    int cnt  = deg[node];          // real edges only

    float4 acc = make_float4(0.f, 0.f, 0.f, 0.f);
    int j = 0;
    for (; j + 2 <= cnt; j += 2) {
        int e = base + j + half;
        int s = csr_src[e];
        float w = csr_wt[e];
        float4 v = *reinterpret_cast<const float4*>(xw + (size_t)s * D + (l32 << 2));
        acc.x += w * v.x; acc.y += w * v.y; acc.z += w * v.z; acc.w += w * v.w;
    }
    if (j < cnt && half == 0) {
        int e = base + j;
        int s = csr_src[e];
        float w = csr_wt[e];
        float4 v = *reinterpret_cast<const float4*>(xw + (size_t)s * D + (l32 << 2));
        acc.x += w * v.x; acc.y += w * v.y; acc.z += w * v.z; acc.w += w * v.w;
    }

    acc.x += __shfl_down(acc.x, 32);
    acc.y += __shfl_down(acc.y, 32);
    acc.z += __shfl_down(acc.z, 32);
    acc.w += __shfl_down(acc.w, 32);

    if (half == 0) {
        float di = dinv[node];
        float4 vs = *reinterpret_cast<const float4*>(xw + (size_t)node * D + (l32 << 2));
        float4 b  = *reinterpret_cast<const float4*>(bias + (l32 << 2));
        float4 r;
        r.x = di * (acc.x + di * vs.x) + b.x;
        r.y = di * (acc.y + di * vs.y) + b.y;
        r.z = di * (acc.z + di * vs.z) + b.z;
        r.w = di * (acc.w + di * vs.w) + b.w;
        if (do_relu) {
            r.x = fmaxf(r.x, 0.f); r.y = fmaxf(r.y, 0.f);
            r.z = fmaxf(r.z, 0.f); r.w = fmaxf(r.w, 0.f);
        }
        *reinterpret_cast<float4*>(outp + (size_t)node * D + (l32 << 2)) = r;
    }
}

// ---------------- head ----------------
__global__ __launch_bounds__(256) void fc_kernel(const float* __restrict__ h,
                                                 const float* __restrict__ Wfc,
                                                 const float* __restrict__ bfc,
                                                 float* __restrict__ outp, int n) {
    int wave = (blockIdx.x * blockDim.x + threadIdx.x) >> 6;
    int lane = threadIdx.x & 63;
    if (wave >= n) return;
    float2 v = *reinterpret_cast<const float2*>(h + (size_t)wave * D + (lane << 1));
    float2 w = *reinterpret_cast<const float2*>(Wfc + (lane << 1));
    float s = v.x * w.x + v.y * w.y;
    #pragma unroll
    for (int off = 32; off > 0; off >>= 1) s += __shfl_down(s, off);
    if (lane == 0) outp[wave] = s + bfc[0];
}

// ---------------- launch ----------------

extern "C" void kernel_launch(void* const* d_in, const int* in_sizes, int n_in,
                              void* d_out, int out_size, void* d_ws, size_t ws_size,
                              hipStream_t stream) {
    const float* x   = (const float*)d_in[0];
    const int*   ei  = (const int*)d_in[1];
    const float* W1  = (const float*)d_in[2];
    const float* b1  = (const float*)d_in[3];
    const float* W2  = (const float*)d_in[4];
    const float* b2  = (const float*)d_in[5];
    const float* W3  = (const float*)d_in[6];
    const float* b3  = (const float*)d_in[7];
    const float* Wfc = (const float*)d_in[8];
    const float* bfc = (const float*)d_in[9];
    float* outp = (float*)d_out;

    const int n = in_sizes[0] / D;        // 50000
    const int e = in_sizes[1] / 2;        // 800000
    const int* src = ei;
    const int* dst = ei + e;

    char* ws = (char*)d_ws;
    size_t off = 0;
    auto alloc = [&](size_t bytes) {
        void* p = ws + off;
        off += (bytes + 255) & ~(size_t)255;
        return p;
    };
    int*   deg     = (int*)alloc((size_t)n * 4);
    int*   cursor  = (int*)alloc((size_t)n * 4);
    size_t zero_bytes = off;              // deg + cursor get memset to 0
    int*   offsets = (int*)alloc((size_t)n * 4);
    float* dinv    = (float*)alloc((size_t)n * 4);
    int*   blkSums = (int*)alloc(64 * 4);
    int*   blkOff  = (int*)alloc(64 * 4);
    int*   csr_src = (int*)alloc((size_t)e * 4);
    float* csr_wt  = (float*)alloc((size_t)e * 4);
    float* buf0    = (float*)alloc((size_t)n * D * 4);
    float* buf1    = (float*)alloc((size_t)n * D * 4);

    int eb256 = (e + 255) / 256;
    int scan_blocks = (n + SCAN_ELEMS - 1) / SCAN_ELEMS;   // 13 for n=50000 (must be <= 64)

    hipMemsetAsync(ws, 0, zero_bytes, stream);
    count_kernel<<<eb256, 256, 0, stream>>>(dst, deg, e);
    scanA_kernel<<<scan_blocks, 256, 0, stream>>>(deg, blkSums, n);
    scanB_kernel<<<1, 64, 0, stream>>>(blkSums, blkOff, scan_blocks);
    scanC_kernel<<<scan_blocks, 256, 0, stream>>>(deg, blkOff, offsets, dinv, n);
    fill_kernel <<<eb256, 256, 0, stream>>>(src, dst, offsets, cursor, dinv, csr_src, csr_wt, e);

    int gemm_blocks = (n + TM - 1) / TM;
    int agg_blocks  = (n + 3) / 4;
    int fc_blocks   = ((size_t)n * 64 + 255) / 256;

    gemm_kernel<<<gemm_blocks, 256, 0, stream>>>(x, W1, buf0, n);
    agg_kernel <<<agg_blocks, 256, 0, stream>>>(buf0, csr_src, csr_wt, offsets, deg, dinv, b1, buf1, n, 1);
    gemm_kernel<<<gemm_blocks, 256, 0, stream>>>(buf1, W2, buf0, n);
    agg_kernel <<<agg_blocks, 256, 0, stream>>>(buf0, csr_src, csr_wt, offsets, deg, dinv, b2, buf1, n, 1);
    gemm_kernel<<<gemm_blocks, 256, 0, stream>>>(buf1, W3, buf0, n);
    agg_kernel <<<agg_blocks, 256, 0, stream>>>(buf0, csr_src, csr_wt, offsets, deg, dinv, b3, buf1, n, 1);
    fc_kernel  <<<fc_blocks, 256, 0, stream>>>(buf1, Wfc, bfc, outp, n);
}

// Round 3
// 437.822 us; speedup vs baseline: 1.2754x; 1.1479x over previous
//
#include <hip/hip_runtime.h>

#define D 128
#define GTM 32
#define SCAN_ELEMS 4096   // elements per scan block (256 threads x 16)

// ---------------- precompute kernels ----------------
// deg[] counts REAL edges only (self-loop handled as +1 at use sites).

__global__ void count_kernel(const int* __restrict__ dst, int* __restrict__ deg, int e) {
    int i = blockIdx.x * blockDim.x + threadIdx.x;
    if (i < e) atomicAdd(&deg[dst[i]], 1);
}

// ---- hierarchical scan: A) block sums  B) scan block sums  C) final offsets + dinv ----

__global__ __launch_bounds__(256) void scanA_kernel(const int* __restrict__ deg,
                                                    int* __restrict__ blkSums, int n) {
    __shared__ int waveSums[4];
    int t = threadIdx.x;
    int base = blockIdx.x * SCAN_ELEMS + t * 16;
    int s = 0;
    if (base + 16 <= n) {
        const int4* p = reinterpret_cast<const int4*>(deg + base);
        #pragma unroll
        for (int k = 0; k < 4; ++k) {
            int4 v = p[k];
            s += v.x + v.y + v.z + v.w;
        }
    } else {
        for (int k = 0; k < 16; ++k) {
            int i = base + k;
            if (i < n) s += deg[i];
        }
    }
    #pragma unroll
    for (int off = 32; off > 0; off >>= 1) s += __shfl_down(s, off);
    int lane = t & 63, w = t >> 6;
    if (lane == 0) waveSums[w] = s;
    __syncthreads();
    if (t == 0) blkSums[blockIdx.x] = waveSums[0] + waveSums[1] + waveSums[2] + waveSums[3];
}

__global__ void scanB_kernel(const int* __restrict__ blkSums, int* __restrict__ blkOff, int nblk) {
    int t = threadIdx.x;   // 64 threads
    int s = (t < nblk) ? blkSums[t] : 0;
    int orig = s;
    #pragma unroll
    for (int off = 1; off < 64; off <<= 1) {
        int u = __shfl_up(s, off);
        if (t >= off) s += u;
    }
    if (t < nblk) blkOff[t] = s - orig;   // exclusive
}

__global__ __launch_bounds__(256) void scanC_kernel(const int* __restrict__ deg,
                                                    const int* __restrict__ blkOff,
                                                    int* __restrict__ offsets,
                                                    float* __restrict__ dinv, int n) {
    __shared__ int waveSums[4];
    int t = threadIdx.x;
    int lane = t & 63, w = t >> 6;
    int base = blockIdx.x * SCAN_ELEMS + t * 16;

    int v[16];
    int s = 0;
    #pragma unroll
    for (int k = 0; k < 16; ++k) {
        int i = base + k;
        int d = (i < n) ? deg[i] : 0;
        v[k] = d;
        s += d;
    }
    int incl = s;
    #pragma unroll
    for (int off = 1; off < 64; off <<= 1) {
        int u = __shfl_up(incl, off);
        if (lane >= off) incl += u;
    }
    if (lane == 63) waveSums[w] = incl;
    __syncthreads();
    int waveOff = 0;
    for (int i = 0; i < 4; ++i) if (i < w) waveOff += waveSums[i];
    int off0 = blkOff[blockIdx.x] + waveOff + incl - s;

    #pragma unroll
    for (int k = 0; k < 16; ++k) {
        int i = base + k;
        if (i < n) {
            offsets[i] = off0;
            dinv[i] = rsqrtf((float)(v[k] + 1));   // +1 self-loop
            off0 += v[k];
        }
    }
}

__global__ void fill_kernel(const int* __restrict__ src, const int* __restrict__ dst,
                            const int* __restrict__ offsets, int* __restrict__ cursor,
                            int* __restrict__ csr_src, int e) {
    int i = blockIdx.x * blockDim.x + threadIdx.x;
    if (i < e) {
        int d = dst[i];
        int pos = offsets[d] + atomicAdd(&cursor[d], 1);
        csr_src[pos] = src[i];
    }
}

// ---------------- dense transform: out[r][c] = dinv[r] * (A[r][:] @ W[:][c]) ----------------
// 1-wave blocks, 32 rows/block, 8x8 register tile, k staged in quarters of 32.
// LDS = 4.6KB (AsT) + 16.9KB (Ws) = 21.5KB -> 7 blocks/CU; 1563 blocks all co-resident.
__global__ __launch_bounds__(64, 2) void gemm_kernel(const float* __restrict__ A,
                                                     const float* __restrict__ Wg,
                                                     const float* __restrict__ dinv,
                                                     float* __restrict__ outp, int n) {
    __shared__ float AsT[32][36];   // [k][row], row-pad 36 (144B rows, 16B aligned)
    __shared__ float Ws[32][132];   // [k][col]

    int t = threadIdx.x;
    int rowBase = blockIdx.x * GTM;
    int rb = (t >> 4) << 3;         // 0,8,16,24
    int cb = (t & 15) << 3;         // 0..120
    float acc[8][8] = {};

    for (int kp = 0; kp < 128; kp += 32) {
        __syncthreads();
        // stage A transposed: rows rowBase..+31, cols kp..kp+31
        {
            int r  = t >> 3;            // 0..7
            int c4 = (t & 7) << 2;      // 0..28
            #pragma unroll
            for (int i = 0; i < 4; ++i) {
                int gr = rowBase + r + i * 8;
                float4 v = (gr < n) ? *reinterpret_cast<const float4*>(A + (size_t)gr * D + kp + c4)
                                    : make_float4(0.f, 0.f, 0.f, 0.f);
                AsT[c4 + 0][r + i * 8] = v.x;
                AsT[c4 + 1][r + i * 8] = v.y;
                AsT[c4 + 2][r + i * 8] = v.z;
                AsT[c4 + 3][r + i * 8] = v.w;
            }
        }
        // stage W rows kp..kp+31, all 128 cols
        {
            int kk0 = t >> 5;           // 0..1
            int c4  = (t & 31) << 2;    // 0..124
            #pragma unroll
            for (int i = 0; i < 16; ++i) {
                int kk = kk0 + i * 2;
                *reinterpret_cast<float4*>(&Ws[kk][c4]) =
                    *reinterpret_cast<const float4*>(Wg + (size_t)(kp + kk) * D + c4);
            }
        }
        __syncthreads();

        #pragma unroll 8
        for (int kk = 0; kk < 32; ++kk) {
            float4 a0 = *reinterpret_cast<const float4*>(&AsT[kk][rb]);
            float4 a1 = *reinterpret_cast<const float4*>(&AsT[kk][rb + 4]);
            float4 w0 = *reinterpret_cast<const float4*>(&Ws[kk][cb]);
            float4 w1 = *reinterpret_cast<const float4*>(&Ws[kk][cb + 4]);
            float a[8] = {a0.x, a0.y, a0.z, a0.w, a1.x, a1.y, a1.z, a1.w};
            float w[8] = {w0.x, w0.y, w0.z, w0.w, w1.x, w1.y, w1.z, w1.w};
            #pragma unroll
            for (int r = 0; r < 8; ++r) {
                #pragma unroll
                for (int c = 0; c < 8; ++c) acc[r][c] += a[r] * w[c];
            }
        }
    }

    #pragma unroll
    for (int r = 0; r < 8; ++r) {
        int gr = rowBase + rb + r;
        if (gr < n) {
            float s = dinv[gr];
            float4 o0, o1;
            o0.x = acc[r][0] * s; o0.y = acc[r][1] * s; o0.z = acc[r][2] * s; o0.w = acc[r][3] * s;
            o1.x = acc[r][4] * s; o1.y = acc[r][5] * s; o1.z = acc[r][6] * s; o1.w = acc[r][7] * s;
            float* o = outp + (size_t)gr * D + cb;
            *reinterpret_cast<float4*>(o)     = o0;
            *reinterpret_cast<float4*>(o + 4) = o1;
        }
    }
}

// ---------------- aggregation (+ optional fused fc head) ----------------
// xws rows are pre-scaled by dinv[row]:
//   h[d] = relu( dinv[d] * (sum_{e:s->d} xws[s] + xws[d]) + b )
// If fcw != null: out[d] = h[d] . Wfc + bfc  (h not stored)
__global__ __launch_bounds__(256) void agg_kernel(const float* __restrict__ xws,
                                                  const int* __restrict__ csr_src,
                                                  const int* __restrict__ offsets,
                                                  const int* __restrict__ deg,
                                                  const float* __restrict__ dinv,
                                                  const float* __restrict__ bias,
                                                  float* __restrict__ outp,
                                                  const float* __restrict__ fcw,
                                                  const float* __restrict__ fcb,
                                                  float* __restrict__ fcout,
                                                  int n) {
    int wave = (blockIdx.x * blockDim.x + threadIdx.x) >> 6;
    int lane = threadIdx.x & 63;
    if (wave >= n) return;
    int node = wave;
    int half = lane >> 5;
    int l32  = lane & 31;

    int base = offsets[node];
    int cnt  = deg[node];

    float4 acc0 = make_float4(0.f, 0.f, 0.f, 0.f);
    float4 acc1 = make_float4(0.f, 0.f, 0.f, 0.f);
    int j = 0;
    for (; j + 4 <= cnt; j += 4) {
        int e0 = base + j + half;
        int e1 = base + j + 2 + half;
        int s0 = csr_src[e0];
        int s1 = csr_src[e1];
        float4 v0 = *reinterpret_cast<const float4*>(xws + (size_t)s0 * D + (l32 << 2));
        float4 v1 = *reinterpret_cast<const float4*>(xws + (size_t)s1 * D + (l32 << 2));
        acc0.x += v0.x; acc0.y += v0.y; acc0.z += v0.z; acc0.w += v0.w;
        acc1.x += v1.x; acc1.y += v1.y; acc1.z += v1.z; acc1.w += v1.w;
    }
    int rem = cnt - j;
    if (half < rem) {
        int s = csr_src[base + j + half];
        float4 v = *reinterpret_cast<const float4*>(xws + (size_t)s * D + (l32 << 2));
        acc0.x += v.x; acc0.y += v.y; acc0.z += v.z; acc0.w += v.w;
    }
    if (rem == 3 && half == 0) {
        int s = csr_src[base + j + 2];
        float4 v = *reinterpret_cast<const float4*>(xws + (size_t)s * D + (l32 << 2));
        acc1.x += v.x; acc1.y += v.y; acc1.z += v.z; acc1.w += v.w;
    }

    acc0.x += acc1.x; acc0.y += acc1.y; acc0.z += acc1.z; acc0.w += acc1.w;
    acc0.x += __shfl_down(acc0.x, 32);
    acc0.y += __shfl_down(acc0.y, 32);
    acc0.z += __shfl_down(acc0.z, 32);
    acc0.w += __shfl_down(acc0.w, 32);

    // compute h fragment (valid in lanes 0..31 after fold)
    float di = dinv[node];
    float4 vs = *reinterpret_cast<const float4*>(xws + (size_t)node * D + (l32 << 2));
    float4 b  = *reinterpret_cast<const float4*>(bias + (l32 << 2));
    float4 r;
    r.x = fmaxf(di * (acc0.x + vs.x) + b.x, 0.f);
    r.y = fmaxf(di * (acc0.y + vs.y) + b.y, 0.f);
    r.z = fmaxf(di * (acc0.z + vs.z) + b.z, 0.f);
    r.w = fmaxf(di * (acc0.w + vs.w) + b.w, 0.f);

    if (fcw == nullptr) {
        if (half == 0)
            *reinterpret_cast<float4*>(outp + (size_t)node * D + (l32 << 2)) = r;
    } else {
        float4 wv = *reinterpret_cast<const float4*>(fcw + (l32 << 2));
        float s = (half == 0) ? (r.x * wv.x + r.y * wv.y + r.z * wv.z + r.w * wv.w) : 0.f;
        #pragma unroll
        for (int off = 32; off > 0; off >>= 1) s += __shfl_down(s, off);
        if (lane == 0) fcout[node] = s + fcb[0];
    }
}

// ---------------- launch ----------------

extern "C" void kernel_launch(void* const* d_in, const int* in_sizes, int n_in,
                              void* d_out, int out_size, void* d_ws, size_t ws_size,
                              hipStream_t stream) {
    const float* x   = (const float*)d_in[0];
    const int*   ei  = (const int*)d_in[1];
    const float* W1  = (const float*)d_in[2];
    const float* b1  = (const float*)d_in[3];
    const float* W2  = (const float*)d_in[4];
    const float* b2  = (const float*)d_in[5];
    const float* W3  = (const float*)d_in[6];
    const float* b3  = (const float*)d_in[7];
    const float* Wfc = (const float*)d_in[8];
    const float* bfc = (const float*)d_in[9];
    float* outp = (float*)d_out;

    const int n = in_sizes[0] / D;        // 50000
    const int e = in_sizes[1] / 2;        // 800000
    const int* src = ei;
    const int* dst = ei + e;

    char* ws = (char*)d_ws;
    size_t off = 0;
    auto alloc = [&](size_t bytes) {
        void* p = ws + off;
        off += (bytes + 255) & ~(size_t)255;
        return p;
    };
    int*   deg     = (int*)alloc((size_t)n * 4);
    int*   cursor  = (int*)alloc((size_t)n * 4);
    size_t zero_bytes = off;              // deg + cursor zeroed
    int*   offsets = (int*)alloc((size_t)n * 4);
    float* dinv    = (float*)alloc((size_t)n * 4);
    int*   blkSums = (int*)alloc(64 * 4);
    int*   blkOff  = (int*)alloc(64 * 4);
    int*   csr_src = (int*)alloc((size_t)e * 4);
    float* buf0    = (float*)alloc((size_t)n * D * 4);
    float* buf1    = (float*)alloc((size_t)n * D * 4);

    int eb256 = (e + 255) / 256;
    int scan_blocks = (n + SCAN_ELEMS - 1) / SCAN_ELEMS;   // 13 (<=64)

    hipMemsetAsync(ws, 0, zero_bytes, stream);
    count_kernel<<<eb256, 256, 0, stream>>>(dst, deg, e);
    scanA_kernel<<<scan_blocks, 256, 0, stream>>>(deg, blkSums, n);
    scanB_kernel<<<1, 64, 0, stream>>>(blkSums, blkOff, scan_blocks);
    scanC_kernel<<<scan_blocks, 256, 0, stream>>>(deg, blkOff, offsets, dinv, n);
    fill_kernel <<<eb256, 256, 0, stream>>>(src, dst, offsets, cursor, csr_src, e);

    int gemm_blocks = (n + GTM - 1) / GTM;   // 1563
    int agg_blocks  = (n + 3) / 4;

    gemm_kernel<<<gemm_blocks, 64, 0, stream>>>(x, W1, dinv, buf0, n);
    agg_kernel <<<agg_blocks, 256, 0, stream>>>(buf0, csr_src, offsets, deg, dinv, b1, buf1,
                                                nullptr, nullptr, nullptr, n);
    gemm_kernel<<<gemm_blocks, 64, 0, stream>>>(buf1, W2, dinv, buf0, n);
    agg_kernel <<<agg_blocks, 256, 0, stream>>>(buf0, csr_src, offsets, deg, dinv, b2, buf1,
                                                nullptr, nullptr, nullptr, n);
    gemm_kernel<<<gemm_blocks, 64, 0, stream>>>(buf1, W3, dinv, buf0, n);
    agg_kernel <<<agg_blocks, 256, 0, stream>>>(buf0, csr_src, offsets, deg, dinv, b3, nullptr,
                                                Wfc, bfc, outp, n);
}